// Round 7
// baseline (150.066 us; speedup 1.0000x reference)
//
#include <hip/hip_runtime.h>
#include <hip/hip_bf16.h>
#include <stdint.h>

#define B_ 32
#define S_ 8192
#define HD_ 256
#define HE_ 256
#define CHUNK 256
#define ROWS 16              /* rows per step */
#define MSTEPS (CHUNK/ROWS)  /* 16 steps */
#define NCHUNK (S_/CHUNK)    /* 32 chunks per batch */

typedef __attribute__((ext_vector_type(8))) short bf16x8;
typedef __attribute__((ext_vector_type(4))) float f32x4;

__device__ __forceinline__ uint32_t cvt_pk_bf16(float lo, float hi) {
  uint32_t r;
  asm("v_cvt_pk_bf16_f32 %0, %1, %2" : "=v"(r) : "v"(lo), "v"(hi));
  return r;
}
__device__ __forceinline__ float bf2f(unsigned short h) {
  return __uint_as_float(((uint32_t)h) << 16);
}
__device__ __forceinline__ float tanh_fast(float x) {
  // tanh(x) = 1 - 2/(exp(2x)+1); well-behaved at +/-inf, no NaN
  float e = __expf(2.0f * x);
  return 1.0f - 2.0f * __builtin_amdgcn_rcpf(e + 1.0f);
}

// ---------------- prep: qv[b,h] = q@Wa^T + Wa_b + Ua_b ; Ua -> bf16 ----------------
__global__ void prep_kernel(const float* __restrict__ query,
                            const float* __restrict__ Wa_w,
                            const float* __restrict__ Wa_b,
                            const float* __restrict__ Ua_w,
                            const float* __restrict__ Ua_b,
                            float* __restrict__ qv,
                            unsigned short* __restrict__ ua_bf) {
  const int blk = blockIdx.x, t = threadIdx.x;
  if (blk < B_) {
    __shared__ float qs[HD_];
    qs[t] = query[blk * HD_ + t];
    __syncthreads();
    const float* wr = Wa_w + (size_t)t * HD_;
    float s = Wa_b[t] + Ua_b[t];
#pragma unroll 8
    for (int d = 0; d < HD_; ++d) s += qs[d] * wr[d];
    qv[blk * HD_ + t] = s;
  } else {
    const int base = (blk - B_) * 2048 + t * 8;
    float4 v0 = *(const float4*)(Ua_w + base);
    float4 v1 = *(const float4*)(Ua_w + base + 4);
    uint4 pk;
    pk.x = cvt_pk_bf16(v0.x, v0.y);
    pk.y = cvt_pk_bf16(v0.z, v0.w);
    pk.z = cvt_pk_bf16(v1.x, v1.y);
    pk.w = cvt_pk_bf16(v1.z, v1.w);
    *(uint4*)(ua_bf + base) = pk;
  }
}

// ---------------- main: fused k_proj GEMM + tanh + score-exp + context partial ----------------
// 512 threads = 8 waves. Wave w owns h-slice [32w,32w+32) with Ua frags in regs (read once).
// 16-row M-steps, dual-buffered bf16 LDS tiles, 2 barriers/step:
//   [issue loads; MFMA(cur); tanh; reduce -> sc]  B1
//   [per-wave redundant row-sum+exp (shfl bcast); numerator(cur); cvt_pk+stage(nxt)]  B2
__global__ __launch_bounds__(512)
__attribute__((amdgpu_waves_per_eu(4, 4)))
void main_kernel(const float* __restrict__ keys,
                 const float* __restrict__ qv,
                 const float* __restrict__ Va_w,
                 const unsigned short* __restrict__ ua_bf,
                 float* __restrict__ wexp_g,
                 float* __restrict__ partials) {
  __shared__ __align__(16) char kt[2 * ROWS * 512];   // 2 x (16 rows x 512B bf16), swizzled
  __shared__ float sc[ROWS][9];                        // per-row, per-wave score partials
  __shared__ float num2[512];

  const int t = threadIdx.x;
  const int b = blockIdx.y;
  const int chunk = blockIdx.x;
  const int s0 = chunk * CHUNK;
  const int lane = t & 63;
  const int w = t >> 6;
  const int ln = lane & 15;
  const int hi = lane >> 4;

  // ---- B fragments: wave w's 32 h-cols, 2 h-tiles, read ONCE (64 regs) ----
  const unsigned short* ub0 = ua_bf + (size_t)(w * 32 + ln) * HE_ + hi * 8;
  const unsigned short* ub1 = ub0 + 16 * HE_;
  bf16x8 bb0[8], bb1[8];
#pragma unroll
  for (int k = 0; k < 8; ++k) {
    bb0[k] = *(const bf16x8*)(ub0 + k * 32);
    bb1[k] = *(const bf16x8*)(ub1 + k * 32);
  }
  const float q0  = qv[b * HD_ + w * 32 + ln];
  const float q1  = qv[b * HD_ + w * 32 + 16 + ln];
  const float va0 = Va_w[w * 32 + ln];
  const float va1 = Va_w[w * 32 + 16 + ln];

  // ---- staging geometry: thread t handles row t>>5, 16B bf16 chunk t&31 ----
  const int srow = t >> 5;            // 0..15
  const int scch = t & 31;            // 16B bf16 chunk within 512B row
  const float* ksrc = keys + ((size_t)b * S_ + s0 + srow) * HE_ + scch * 8;
  const int ldsoff = srow * 512 + ((scch * 16) ^ ((srow & 7) << 4));

  // ---- prologue: stage step 0 into buffer 0 ----
  {
    float4 a0 = *(const float4*)(ksrc);
    float4 a1 = *(const float4*)(ksrc + 4);
    uint4 pk;
    pk.x = cvt_pk_bf16(a0.x, a0.y);
    pk.y = cvt_pk_bf16(a0.z, a0.w);
    pk.z = cvt_pk_bf16(a1.x, a1.y);
    pk.w = cvt_pk_bf16(a1.z, a1.w);
    *(uint4*)(kt + ldsoff) = pk;
  }
  __syncthreads();

  const int half = t >> 8;            // numerator row-half (0/1)
  const int e2 = (t & 255) * 2;       // numerator column byte offset (bf16)
  const int asw = (ln & 7) << 4;      // A-frag row swizzle
  float num = 0.f;

#pragma unroll 1
  for (int i = 0; i < MSTEPS; ++i) {
    char* cur = kt + (i & 1) * (ROWS * 512);
    char* nxt = kt + ((i + 1) & 1) * (ROWS * 512);

    // issue next-step global loads early (T14: issue-early / write-late)
    float4 ga0, ga1;
    if (i + 1 < MSTEPS) {
      const float* kA = ksrc + (size_t)(i + 1) * ROWS * HE_;
      ga0 = *(const float4*)(kA);
      ga1 = *(const float4*)(kA + 4);
    }

    // ---- MFMA: 1 M-subtile x 2 h-tiles; A-frags just-in-time from LDS ----
    f32x4 a00 = {0.f,0.f,0.f,0.f}, a01 = {0.f,0.f,0.f,0.f};
    const char* arow = cur + ln * 512;
#pragma unroll
    for (int k = 0; k < 8; ++k) {
      bf16x8 af = *(const bf16x8*)(arow + ((k * 64 + hi * 16) ^ asw));
      a00 = __builtin_amdgcn_mfma_f32_16x16x32_bf16(af, bb0[k], a00, 0, 0, 0);
      a01 = __builtin_amdgcn_mfma_f32_16x16x32_bf16(af, bb1[k], a01, 0, 0, 0);
    }

    // ---- per-row partial over this wave's 32 h-cols ----
#pragma unroll
    for (int r = 0; r < 4; ++r) {
      float v0 = tanh_fast(a00[r] + q0) * va0 + tanh_fast(a01[r] + q1) * va1;
      v0 += __shfl_xor(v0, 1, 64);
      v0 += __shfl_xor(v0, 2, 64);
      v0 += __shfl_xor(v0, 4, 64);
      v0 += __shfl_xor(v0, 8, 64);
      if (ln == 0) sc[hi * 4 + r][w] = v0;
    }
    __syncthreads();   // B1: sc complete

    // ---- per-wave redundant row-sum + exp (lanes 0..15), shfl broadcast ----
    float e = 0.f;
    if (lane < 16) {
      float s = sc[lane][0];
#pragma unroll
      for (int ww = 1; ww < 8; ++ww) s += sc[lane][ww];
      e = __expf(s);     // no max shift: scores bounded by sum|Va|
    }
    if (t < 16) wexp_g[(size_t)b * S_ + s0 + i * ROWS + t] = e;

    // ---- context numerator for this tile (cur still valid) ----
#pragma unroll
    for (int rr = 0; rr < 8; ++rr) {
      const int row = half * 8 + rr;
      const float wrow = __shfl(e, row, 64);
      unsigned short kv = *(const unsigned short*)(cur + row * 512 + (e2 ^ ((row & 7) << 4)));
      num += wrow * bf2f(kv);
    }

    // ---- stage-write next tile ----
    if (i + 1 < MSTEPS) {
      uint4 pk;
      pk.x = cvt_pk_bf16(ga0.x, ga0.y);
      pk.y = cvt_pk_bf16(ga0.z, ga0.w);
      pk.z = cvt_pk_bf16(ga1.x, ga1.y);
      pk.w = cvt_pk_bf16(ga1.z, ga1.w);
      *(uint4*)(nxt + ldsoff) = pk;
    }
    __syncthreads();   // B2: nxt staged, cur free
  }

  num2[t] = num;
  __syncthreads();
  if (t < 256) {
    partials[((size_t)b * NCHUNK + chunk) * 256 + t] = num2[t] + num2[t + 256];
  }
}

// ---------------- combine: den + context + weights per batch ----------------
__global__ void combine_kernel(const float* __restrict__ wexp_g,
                               const float* __restrict__ partials,
                               float* __restrict__ out) {
  __shared__ float red[4];
  __shared__ float rdsh;
  const int b = blockIdx.x, t = threadIdx.x;   // 256 threads
  const float* we = wexp_g + (size_t)b * S_;
  float s = 0.f;
#pragma unroll 4
  for (int i = t; i < S_; i += 256) s += we[i];
#pragma unroll
  for (int mm = 32; mm; mm >>= 1) s += __shfl_xor(s, mm, 64);
  if ((t & 63) == 0) red[t >> 6] = s;
  __syncthreads();
  if (t == 0) rdsh = 1.0f / (red[0] + red[1] + red[2] + red[3]);
  __syncthreads();
  const float rd = rdsh;

  const float* pb = partials + (size_t)b * NCHUNK * 256;
  float num = 0.f;
#pragma unroll 4
  for (int i = 0; i < NCHUNK; ++i) num += pb[i * 256 + t];
  out[b * HE_ + t] = num * rd;

  float* wout = out + B_ * HE_ + (size_t)b * S_;
#pragma unroll 4
  for (int i = t; i < S_; i += 256) wout[i] = we[i] * rd;
}

extern "C" void kernel_launch(void* const* d_in, const int* in_sizes, int n_in,
                              void* d_out, int out_size, void* d_ws, size_t ws_size,
                              hipStream_t stream) {
  const float* query = (const float*)d_in[0];
  const float* keys  = (const float*)d_in[1];
  const float* Wa_w  = (const float*)d_in[2];
  const float* Wa_b  = (const float*)d_in[3];
  const float* Ua_w  = (const float*)d_in[4];
  const float* Ua_b  = (const float*)d_in[5];
  const float* Va_w  = (const float*)d_in[6];
  // Va_b (d_in[7]) is a constant score shift: softmax-invariant, dropped.
  float* out = (float*)d_out;

  char* ws = (char*)d_ws;
  float* qv             = (float*)ws;                               // 32 KB
  unsigned short* ua_bf = (unsigned short*)(ws + 32 * 1024);        // 128 KB
  float* wexp_g         = (float*)(ws + 160 * 1024);                // 1 MB
  float* partials       = (float*)(ws + 160 * 1024 + 1048576);      // 1 MB

  prep_kernel<<<64, 256, 0, stream>>>(query, Wa_w, Wa_b, Ua_w, Ua_b, qv, ua_bf);
  dim3 g(NCHUNK, B_);
  main_kernel<<<g, 512, 0, stream>>>(keys, qv, Va_w, ua_bf, wexp_g, partials);
  combine_kernel<<<B_, 256, 0, stream>>>(wexp_g, partials, out);
}

// Round 9
// 89.071 us; speedup vs baseline: 1.6848x; 1.6848x over previous
//
#include <hip/hip_runtime.h>
#include <hip/hip_bf16.h>
#include <stdint.h>

#define B_ 32
#define S_ 8192
#define HD_ 256
#define HE_ 256
#define CHUNK 256
#define ROWS 16              /* rows per step */
#define MSTEPS (CHUNK/ROWS)  /* 16 steps */
#define NCHUNK (S_/CHUNK)    /* 32 chunks per batch */

typedef __attribute__((ext_vector_type(8))) short bf16x8;
typedef __attribute__((ext_vector_type(4))) float f32x4;

__device__ __forceinline__ uint32_t cvt_pk_bf16(float lo, float hi) {
  uint32_t r;
  asm("v_cvt_pk_bf16_f32 %0, %1, %2" : "=v"(r) : "v"(lo), "v"(hi));
  return r;
}
__device__ __forceinline__ float bf2f(unsigned short h) {
  return __uint_as_float(((uint32_t)h) << 16);
}
__device__ __forceinline__ float tanh_fast(float x) {
  // tanh(x) = 1 - 2/(exp(2x)+1); well-behaved at +/-inf, no NaN
  float e = __expf(2.0f * x);
  return 1.0f - 2.0f * __builtin_amdgcn_rcpf(e + 1.0f);
}
// VALU cross-lane add within 16-lane DPP rows (no DS-unit traffic).
// row_shr:N -> dest lane i receives src lane i-N (lanes <N get 0 w/ bound_ctrl).
// After shr 8,4,2,1 the 16-lane sum lands in lane 15 of each row.
template<int CTRL>
__device__ __forceinline__ float dpp_shr_add(float v) {
  int t = __builtin_amdgcn_update_dpp(0, __float_as_int(v), CTRL, 0xf, 0xf, true);
  return v + __int_as_float(t);
}
__device__ __forceinline__ float row16_sum(float v) {
  v = dpp_shr_add<0x118>(v);   // row_shr:8
  v = dpp_shr_add<0x114>(v);   // row_shr:4
  v = dpp_shr_add<0x112>(v);   // row_shr:2
  v = dpp_shr_add<0x111>(v);   // row_shr:1
  return v;                     // full sum valid in lane 15 of each 16-lane row
}

// ---------------- prep: qv[b,h] = q@Wa^T + Wa_b + Ua_b ; Ua -> bf16 ----------------
__global__ void prep_kernel(const float* __restrict__ query,
                            const float* __restrict__ Wa_w,
                            const float* __restrict__ Wa_b,
                            const float* __restrict__ Ua_w,
                            const float* __restrict__ Ua_b,
                            float* __restrict__ qv,
                            unsigned short* __restrict__ ua_bf) {
  const int blk = blockIdx.x, t = threadIdx.x;
  if (blk < B_) {
    __shared__ float qs[HD_];
    qs[t] = query[blk * HD_ + t];
    __syncthreads();
    const float* wr = Wa_w + (size_t)t * HD_;
    float s = Wa_b[t] + Ua_b[t];
#pragma unroll 8
    for (int d = 0; d < HD_; ++d) s += qs[d] * wr[d];
    qv[blk * HD_ + t] = s;
  } else {
    const int base = (blk - B_) * 2048 + t * 8;
    float4 v0 = *(const float4*)(Ua_w + base);
    float4 v1 = *(const float4*)(Ua_w + base + 4);
    uint4 pk;
    pk.x = cvt_pk_bf16(v0.x, v0.y);
    pk.y = cvt_pk_bf16(v0.z, v0.w);
    pk.z = cvt_pk_bf16(v1.x, v1.y);
    pk.w = cvt_pk_bf16(v1.z, v1.w);
    *(uint4*)(ua_bf + base) = pk;
  }
}

// ---------------- main: fused k_proj GEMM + tanh + score-exp + context partial ----------------
// R4 structure (best measured): 512 threads = 8 waves, wave w owns h-slice [32w,32w+32)
// with Ua frags in regs; 16-row steps, dual-buffered bf16 LDS tiles, 3 barriers/step.
// v9: DPP row-reduce (VALU, sum in lane 15) instead of shfl_xor (DS), cvt_pk staging,
// numerator before stage-write. Loop fully unrollable (static trip count, i&1 buffers).
__global__ __launch_bounds__(512)
__attribute__((amdgpu_waves_per_eu(4, 4)))
void main_kernel(const float* __restrict__ keys,
                 const float* __restrict__ qv,
                 const float* __restrict__ Va_w,
                 const unsigned short* __restrict__ ua_bf,
                 float* __restrict__ wexp_g,
                 float* __restrict__ partials) {
  __shared__ __align__(16) char kt[2 * ROWS * 512];   // 2 x (16 rows x 512B bf16), swizzled
  __shared__ float sc[ROWS][9];                        // per-row, per-wave score partials
  __shared__ float swp[ROWS];                          // per-row exp(score)
  __shared__ float num2[512];

  const int t = threadIdx.x;
  const int b = blockIdx.y;
  const int chunk = blockIdx.x;
  const int s0 = chunk * CHUNK;
  const int lane = t & 63;
  const int w = t >> 6;
  const int ln = lane & 15;
  const int hi = lane >> 4;

  // ---- B fragments: wave w's 32 h-cols, 2 h-tiles, read ONCE (64 regs, AGPR-side) ----
  const unsigned short* ub0 = ua_bf + (size_t)(w * 32 + ln) * HE_ + hi * 8;
  const unsigned short* ub1 = ub0 + 16 * HE_;
  bf16x8 bb0[8], bb1[8];
#pragma unroll
  for (int k = 0; k < 8; ++k) {
    bb0[k] = *(const bf16x8*)(ub0 + k * 32);
    bb1[k] = *(const bf16x8*)(ub1 + k * 32);
  }
  const float q0  = qv[b * HD_ + w * 32 + ln];
  const float q1  = qv[b * HD_ + w * 32 + 16 + ln];
  const float va0 = Va_w[w * 32 + ln];
  const float va1 = Va_w[w * 32 + 16 + ln];

  // ---- staging geometry: thread t handles row t>>5, 16B bf16 chunk t&31 ----
  const int srow = t >> 5;            // 0..15
  const int scch = t & 31;            // 16B bf16 chunk within 512B row
  const float* ksrc = keys + ((size_t)b * S_ + s0 + srow) * HE_ + scch * 8;
  const int ldsoff = srow * 512 + ((scch * 16) ^ ((srow & 7) << 4));

  // ---- prologue: stage step 0 into buffer 0 ----
  {
    float4 a0 = *(const float4*)(ksrc);
    float4 a1 = *(const float4*)(ksrc + 4);
    uint4 pk;
    pk.x = cvt_pk_bf16(a0.x, a0.y);
    pk.y = cvt_pk_bf16(a0.z, a0.w);
    pk.z = cvt_pk_bf16(a1.x, a1.y);
    pk.w = cvt_pk_bf16(a1.z, a1.w);
    *(uint4*)(kt + ldsoff) = pk;
  }
  __syncthreads();

  const int half = t >> 8;            // numerator row-half (0/1)
  const int e2 = (t & 255) * 2;       // numerator column byte offset (bf16)
  const int asw = (ln & 7) << 4;      // A-frag row swizzle
  float num = 0.f;

  for (int i = 0; i < MSTEPS; ++i) {
    char* cur = kt + (i & 1) * (ROWS * 512);
    char* nxt = kt + ((i + 1) & 1) * (ROWS * 512);

    // issue next-step global loads early (T14: issue-early / write-late)
    float4 ga0, ga1;
    if (i + 1 < MSTEPS) {
      const float* kA = ksrc + (size_t)(i + 1) * ROWS * HE_;
      ga0 = *(const float4*)(kA);
      ga1 = *(const float4*)(kA + 4);
    }

    // ---- MFMA: 1 M-subtile x 2 h-tiles; A-frags just-in-time from LDS ----
    f32x4 a00 = {0.f,0.f,0.f,0.f}, a01 = {0.f,0.f,0.f,0.f};
    const char* arow = cur + ln * 512;
#pragma unroll
    for (int k = 0; k < 8; ++k) {
      bf16x8 af = *(const bf16x8*)(arow + ((k * 64 + hi * 16) ^ asw));
      a00 = __builtin_amdgcn_mfma_f32_16x16x32_bf16(af, bb0[k], a00, 0, 0, 0);
      a01 = __builtin_amdgcn_mfma_f32_16x16x32_bf16(af, bb1[k], a01, 0, 0, 0);
    }

    // ---- per-row partial over this wave's 32 h-cols (pure-VALU DPP reduce) ----
#pragma unroll
    for (int r = 0; r < 4; ++r) {
      float v = tanh_fast(a00[r] + q0) * va0 + tanh_fast(a01[r] + q1) * va1;
      v = row16_sum(v);
      if (ln == 15) sc[hi * 4 + r][w] = v;   // lane hi*16+15 holds row hi*4+r sum
    }
    __syncthreads();   // B1: sc complete

    // ---- row score = sum over 8 waves; exp (no max shift: scores bounded) ----
    if (t < ROWS) {
      float s = sc[t][0];
#pragma unroll
      for (int ww = 1; ww < 8; ++ww) s += sc[t][ww];
      float e = __expf(s);
      swp[t] = e;
      wexp_g[(size_t)b * S_ + s0 + i * ROWS + t] = e;
    }
    __syncthreads();   // B2: swp ready

    // ---- context numerator for this tile (LDS only, overlaps vmcnt wait) ----
#pragma unroll
    for (int rr = 0; rr < 8; ++rr) {
      const int row = half * 8 + rr;
      unsigned short kv = *(const unsigned short*)(cur + row * 512 + (e2 ^ ((row & 7) << 4)));
      num += swp[row] * bf2f(kv);
    }

    // ---- stage-write next tile ----
    if (i + 1 < MSTEPS) {
      uint4 pk;
      pk.x = cvt_pk_bf16(ga0.x, ga0.y);
      pk.y = cvt_pk_bf16(ga0.z, ga0.w);
      pk.z = cvt_pk_bf16(ga1.x, ga1.y);
      pk.w = cvt_pk_bf16(ga1.z, ga1.w);
      *(uint4*)(nxt + ldsoff) = pk;
    }
    __syncthreads();   // B3: nxt staged, cur free
  }

  num2[t] = num;
  __syncthreads();
  if (t < 256) {
    partials[((size_t)b * NCHUNK + chunk) * 256 + t] = num2[t] + num2[t + 256];
  }
}

// ---------------- combine: den + context + weights per batch ----------------
__global__ void combine_kernel(const float* __restrict__ wexp_g,
                               const float* __restrict__ partials,
                               float* __restrict__ out) {
  __shared__ float red[4];
  __shared__ float rdsh;
  const int b = blockIdx.x, t = threadIdx.x;   // 256 threads
  const float* we = wexp_g + (size_t)b * S_;
  float s = 0.f;
#pragma unroll 4
  for (int i = t; i < S_; i += 256) s += we[i];
#pragma unroll
  for (int mm = 32; mm; mm >>= 1) s += __shfl_xor(s, mm, 64);
  if ((t & 63) == 0) red[t >> 6] = s;
  __syncthreads();
  if (t == 0) rdsh = 1.0f / (red[0] + red[1] + red[2] + red[3]);
  __syncthreads();
  const float rd = rdsh;

  const float* pb = partials + (size_t)b * NCHUNK * 256;
  float num = 0.f;
#pragma unroll 4
  for (int i = 0; i < NCHUNK; ++i) num += pb[i * 256 + t];
  out[b * HE_ + t] = num * rd;

  float* wout = out + B_ * HE_ + (size_t)b * S_;
#pragma unroll 4
  for (int i = t; i < S_; i += 256) wout[i] = we[i] * rd;
}

extern "C" void kernel_launch(void* const* d_in, const int* in_sizes, int n_in,
                              void* d_out, int out_size, void* d_ws, size_t ws_size,
                              hipStream_t stream) {
  const float* query = (const float*)d_in[0];
  const float* keys  = (const float*)d_in[1];
  const float* Wa_w  = (const float*)d_in[2];
  const float* Wa_b  = (const float*)d_in[3];
  const float* Ua_w  = (const float*)d_in[4];
  const float* Ua_b  = (const float*)d_in[5];
  const float* Va_w  = (const float*)d_in[6];
  // Va_b (d_in[7]) is a constant score shift: softmax-invariant, dropped.
  float* out = (float*)d_out;

  char* ws = (char*)d_ws;
  float* qv             = (float*)ws;                               // 32 KB
  unsigned short* ua_bf = (unsigned short*)(ws + 32 * 1024);        // 128 KB
  float* wexp_g         = (float*)(ws + 160 * 1024);                // 1 MB
  float* partials       = (float*)(ws + 160 * 1024 + 1048576);      // 1 MB

  prep_kernel<<<64, 256, 0, stream>>>(query, Wa_w, Wa_b, Ua_w, Ua_b, qv, ua_bf);
  dim3 g(NCHUNK, B_);
  main_kernel<<<g, 512, 0, stream>>>(keys, qv, Va_w, ua_bf, wexp_g, partials);
  combine_kernel<<<B_, 256, 0, stream>>>(wexp_g, partials, out);
}

// Round 10
// 85.000 us; speedup vs baseline: 1.7655x; 1.0479x over previous
//
#include <hip/hip_runtime.h>
#include <hip/hip_bf16.h>
#include <stdint.h>

#define B_ 32
#define S_ 8192
#define HD_ 256
#define HE_ 256
#define CHUNK 256
#define ROWS 16              /* rows per step */
#define MSTEPS (CHUNK/ROWS)  /* 16 steps */
#define NCHUNK (S_/CHUNK)    /* 32 chunks per batch */

typedef __attribute__((ext_vector_type(8))) short bf16x8;
typedef __attribute__((ext_vector_type(4))) float f32x4;

__device__ __forceinline__ uint32_t cvt_pk_bf16(float lo, float hi) {
  uint32_t r;
  asm("v_cvt_pk_bf16_f32 %0, %1, %2" : "=v"(r) : "v"(lo), "v"(hi));
  return r;
}
__device__ __forceinline__ float bf2f(unsigned short h) {
  return __uint_as_float(((uint32_t)h) << 16);
}
__device__ __forceinline__ float tanh_fast(float x) {
  // tanh(x) = 1 - 2/(exp(2x)+1); well-behaved at +/-inf, no NaN
  float e = __expf(2.0f * x);
  return 1.0f - 2.0f * __builtin_amdgcn_rcpf(e + 1.0f);
}
// VALU cross-lane add within 16-lane DPP rows (no DS-unit traffic).
// row_shr:N -> dest lane i receives src lane i-N. Sum lands in lane 15 of each row.
template<int CTRL>
__device__ __forceinline__ float dpp_shr_add(float v) {
  int t = __builtin_amdgcn_update_dpp(0, __float_as_int(v), CTRL, 0xf, 0xf, true);
  return v + __int_as_float(t);
}
__device__ __forceinline__ float row16_sum(float v) {
  v = dpp_shr_add<0x118>(v);   // row_shr:8
  v = dpp_shr_add<0x114>(v);   // row_shr:4
  v = dpp_shr_add<0x112>(v);   // row_shr:2
  v = dpp_shr_add<0x111>(v);   // row_shr:1
  return v;                     // full sum valid in lane 15 of each 16-lane row
}

// ---------------- prep: qv[b,h] = q@Wa^T + Wa_b + Ua_b ; Ua -> bf16 ----------------
__global__ void prep_kernel(const float* __restrict__ query,
                            const float* __restrict__ Wa_w,
                            const float* __restrict__ Wa_b,
                            const float* __restrict__ Ua_w,
                            const float* __restrict__ Ua_b,
                            float* __restrict__ qv,
                            unsigned short* __restrict__ ua_bf) {
  const int blk = blockIdx.x, t = threadIdx.x;
  if (blk < B_) {
    __shared__ float qs[HD_];
    qs[t] = query[blk * HD_ + t];
    __syncthreads();
    const float* wr = Wa_w + (size_t)t * HD_;
    float s = Wa_b[t] + Ua_b[t];
#pragma unroll 8
    for (int d = 0; d < HD_; ++d) s += qs[d] * wr[d];
    qv[blk * HD_ + t] = s;
  } else {
    const int base = (blk - B_) * 2048 + t * 8;
    float4 v0 = *(const float4*)(Ua_w + base);
    float4 v1 = *(const float4*)(Ua_w + base + 4);
    uint4 pk;
    pk.x = cvt_pk_bf16(v0.x, v0.y);
    pk.y = cvt_pk_bf16(v0.z, v0.w);
    pk.z = cvt_pk_bf16(v1.x, v1.y);
    pk.w = cvt_pk_bf16(v1.z, v1.w);
    *(uint4*)(ua_bf + base) = pk;
  }
}

// ---------------- main: fused k_proj GEMM + tanh + score-exp + context partial ----------------
// 512 threads = 8 waves, wave w owns h-slice [32w,32w+32) with Ua frags in regs.
// v10: 2 barriers/step. Cross-wave score reduce via LDS ds_add_f32 into double-buffered
// sc_sum[2][16]; exp computed redundantly per-wave (2 scalars, registers only);
// numerator as 2 x ds_read_b64 (rows w, w+8; cols 4*lane..4*lane+3) into num4[4].
__global__ __launch_bounds__(512)
__attribute__((amdgpu_waves_per_eu(4, 4)))
void main_kernel(const float* __restrict__ keys,
                 const float* __restrict__ qv,
                 const float* __restrict__ Va_w,
                 const unsigned short* __restrict__ ua_bf,
                 float* __restrict__ wexp_g,
                 float* __restrict__ partials) {
  __shared__ __align__(16) char kt[2 * ROWS * 512];   // 2 x (16 rows x 512B bf16), swizzled
  __shared__ float sc_sum[2][16];                      // double-buffered row scores
  __shared__ __align__(16) float num_l[8][64][4];      // per-wave numerator partials (8 KB)

  const int t = threadIdx.x;
  const int b = blockIdx.y;
  const int chunk = blockIdx.x;
  const int s0 = chunk * CHUNK;
  const int lane = t & 63;
  const int w = t >> 6;
  const int ln = lane & 15;
  const int hi = lane >> 4;

  // ---- B fragments: wave w's 32 h-cols, 2 h-tiles, read ONCE (64 regs) ----
  const unsigned short* ub0 = ua_bf + (size_t)(w * 32 + ln) * HE_ + hi * 8;
  const unsigned short* ub1 = ub0 + 16 * HE_;
  bf16x8 bb0[8], bb1[8];
#pragma unroll
  for (int k = 0; k < 8; ++k) {
    bb0[k] = *(const bf16x8*)(ub0 + k * 32);
    bb1[k] = *(const bf16x8*)(ub1 + k * 32);
  }
  const float q0  = qv[b * HD_ + w * 32 + ln];
  const float q1  = qv[b * HD_ + w * 32 + 16 + ln];
  const float va0 = Va_w[w * 32 + ln];
  const float va1 = Va_w[w * 32 + 16 + ln];

  // ---- staging geometry: thread t handles row t>>5, 16B bf16 chunk t&31 ----
  const int srow = t >> 5;            // 0..15
  const int scch = t & 31;            // 16B bf16 chunk within 512B row
  const float* ksrc = keys + ((size_t)b * S_ + s0 + srow) * HE_ + scch * 8;
  const int ldsoff = srow * 512 + ((scch * 16) ^ ((srow & 7) << 4));

  // ---- prologue: zero both sc_sum buffers; stage step 0 into buffer 0 ----
  if (t < 32) ((float*)sc_sum)[t] = 0.f;
  {
    float4 a0 = *(const float4*)(ksrc);
    float4 a1 = *(const float4*)(ksrc + 4);
    uint4 pk;
    pk.x = cvt_pk_bf16(a0.x, a0.y);
    pk.y = cvt_pk_bf16(a0.z, a0.w);
    pk.z = cvt_pk_bf16(a1.x, a1.y);
    pk.w = cvt_pk_bf16(a1.z, a1.w);
    *(uint4*)(kt + ldsoff) = pk;
  }
  __syncthreads();

  const int asw = (ln & 7) << 4;      // A-frag row swizzle
  const int nsw = (w & 7) << 4;       // numerator row swizzle (rows w and w+8 share it)
  float num4[4] = {0.f, 0.f, 0.f, 0.f};

  for (int i = 0; i < MSTEPS; ++i) {
    char* cur = kt + (i & 1) * (ROWS * 512);
    char* nxt = kt + ((i + 1) & 1) * (ROWS * 512);

    // issue next-step global loads early (T14: issue-early / write-late)
    float4 ga0, ga1;
    if (i + 1 < MSTEPS) {
      const float* kA = ksrc + (size_t)(i + 1) * ROWS * HE_;
      ga0 = *(const float4*)(kA);
      ga1 = *(const float4*)(kA + 4);
    }

    // ---- P1: MFMA (1 M-subtile x 2 h-tiles); A-frags just-in-time from LDS ----
    f32x4 a00 = {0.f,0.f,0.f,0.f}, a01 = {0.f,0.f,0.f,0.f};
    const char* arow = cur + ln * 512;
#pragma unroll
    for (int k = 0; k < 8; ++k) {
      bf16x8 af = *(const bf16x8*)(arow + ((k * 64 + hi * 16) ^ asw));
      a00 = __builtin_amdgcn_mfma_f32_16x16x32_bf16(af, bb0[k], a00, 0, 0, 0);
      a01 = __builtin_amdgcn_mfma_f32_16x16x32_bf16(af, bb1[k], a01, 0, 0, 0);
    }

    // per-row partial over this wave's 32 h-cols -> DPP reduce -> LDS atomic add
#pragma unroll
    for (int r = 0; r < 4; ++r) {
      float v = tanh_fast(a00[r] + q0) * va0 + tanh_fast(a01[r] + q1) * va1;
      v = row16_sum(v);
      if (ln == 15) atomicAdd(&sc_sum[i & 1][hi * 4 + r], v);
    }
    __syncthreads();   // B1: sc_sum complete

    // ---- P2: per-wave exp (registers only) ----
    const float e0 = __expf(sc_sum[i & 1][w]);
    const float e8 = __expf(sc_sum[i & 1][w + 8]);
    if (lane == 0) {
      float* wg = wexp_g + (size_t)b * S_ + s0 + i * ROWS;
      wg[w] = e0;
      wg[w + 8] = e8;
    }
    if (t < 16) sc_sum[(i + 1) & 1][t] = 0.f;   // zero next-step buffer

    // numerator: rows w and w+8, cols 4*lane..4*lane+3 (one b64 read each)
    {
      uint2 kv0 = *(const uint2*)(cur + w * 512 + ((lane * 8) ^ nsw));
      uint2 kv1 = *(const uint2*)(cur + (w + 8) * 512 + ((lane * 8) ^ nsw));
      num4[0] += e0 * bf2f((unsigned short)(kv0.x & 0xffff)) + e8 * bf2f((unsigned short)(kv1.x & 0xffff));
      num4[1] += e0 * bf2f((unsigned short)(kv0.x >> 16))    + e8 * bf2f((unsigned short)(kv1.x >> 16));
      num4[2] += e0 * bf2f((unsigned short)(kv0.y & 0xffff)) + e8 * bf2f((unsigned short)(kv1.y & 0xffff));
      num4[3] += e0 * bf2f((unsigned short)(kv0.y >> 16))    + e8 * bf2f((unsigned short)(kv1.y >> 16));
    }

    // stage-write next tile
    if (i + 1 < MSTEPS) {
      uint4 pk;
      pk.x = cvt_pk_bf16(ga0.x, ga0.y);
      pk.y = cvt_pk_bf16(ga0.z, ga0.w);
      pk.z = cvt_pk_bf16(ga1.x, ga1.y);
      pk.w = cvt_pk_bf16(ga1.z, ga1.w);
      *(uint4*)(nxt + ldsoff) = pk;
    }
    __syncthreads();   // B2: nxt staged, cur free, sc_sum[(i+1)&1] zeroed
  }

  // ---- epilogue: cross-wave numerator reduce ----
  *(float4*)&num_l[w][lane][0] = make_float4(num4[0], num4[1], num4[2], num4[3]);
  __syncthreads();
  if (t < 256) {
    float s = 0.f;
#pragma unroll
    for (int ww = 0; ww < 8; ++ww) s += num_l[ww][t >> 2][t & 3];
    partials[((size_t)b * NCHUNK + chunk) * 256 + t] = s;
  }
}

// ---------------- combine: den + context + weights per batch ----------------
__global__ void combine_kernel(const float* __restrict__ wexp_g,
                               const float* __restrict__ partials,
                               float* __restrict__ out) {
  __shared__ float red[4];
  __shared__ float rdsh;
  const int b = blockIdx.x, t = threadIdx.x;   // 256 threads
  const float* we = wexp_g + (size_t)b * S_;
  float s = 0.f;
#pragma unroll 4
  for (int i = t; i < S_; i += 256) s += we[i];
#pragma unroll
  for (int mm = 32; mm; mm >>= 1) s += __shfl_xor(s, mm, 64);
  if ((t & 63) == 0) red[t >> 6] = s;
  __syncthreads();
  if (t == 0) rdsh = 1.0f / (red[0] + red[1] + red[2] + red[3]);
  __syncthreads();
  const float rd = rdsh;

  const float* pb = partials + (size_t)b * NCHUNK * 256;
  float num = 0.f;
#pragma unroll 4
  for (int i = 0; i < NCHUNK; ++i) num += pb[i * 256 + t];
  out[b * HE_ + t] = num * rd;

  float* wout = out + B_ * HE_ + (size_t)b * S_;
#pragma unroll 4
  for (int i = t; i < S_; i += 256) wout[i] = we[i] * rd;
}

extern "C" void kernel_launch(void* const* d_in, const int* in_sizes, int n_in,
                              void* d_out, int out_size, void* d_ws, size_t ws_size,
                              hipStream_t stream) {
  const float* query = (const float*)d_in[0];
  const float* keys  = (const float*)d_in[1];
  const float* Wa_w  = (const float*)d_in[2];
  const float* Wa_b  = (const float*)d_in[3];
  const float* Ua_w  = (const float*)d_in[4];
  const float* Ua_b  = (const float*)d_in[5];
  const float* Va_w  = (const float*)d_in[6];
  // Va_b (d_in[7]) is a constant score shift: softmax-invariant, dropped.
  float* out = (float*)d_out;

  char* ws = (char*)d_ws;
  float* qv             = (float*)ws;                               // 32 KB
  unsigned short* ua_bf = (unsigned short*)(ws + 32 * 1024);        // 128 KB
  float* wexp_g         = (float*)(ws + 160 * 1024);                // 1 MB
  float* partials       = (float*)(ws + 160 * 1024 + 1048576);      // 1 MB

  prep_kernel<<<64, 256, 0, stream>>>(query, Wa_w, Wa_b, Ua_w, Ua_b, qv, ua_bf);
  dim3 g(NCHUNK, B_);
  main_kernel<<<g, 512, 0, stream>>>(keys, qv, Va_w, ua_bf, wexp_g, partials);
  combine_kernel<<<B_, 256, 0, stream>>>(wexp_g, partials, out);
}